// Round 1
// baseline (190.607 us; speedup 1.0000x reference)
//
#include <hip/hip_runtime.h>

// Problem dims (compile-time constants)
constexpr int B = 16, T = 4096, I = 32, O = 32;
// Chunking: C chunks of L steps, each preceded by W warmup steps from zero
// state. Filters are stable (coeffs ~ N(0,0.1^2), pole radius <~0.75), so
// the wrong-initial-state error decays by <=0.75^64 ~ 1e-8 before the first
// retained output step.
constexpr int C = 16, L = T / C, W = 64;

__global__ __launch_bounds__(256) void mimo_iir_kernel(
    const float* __restrict__ u,    // (B, T, I)
    const float* __restrict__ bcf,  // (O, I, 3)
    const float* __restrict__ acf,  // (O, I, 2)
    float* __restrict__ out)        // (B, T, O)
{
    const int tid = blockIdx.x * 256 + threadIdx.x;
    const int i  = tid & (I - 1);      // input channel = lane within 32-group
    const int g  = tid >> 5;           // group id: (b, c, o), o innermost
    const int o  = g & (O - 1);
    const int bc = g >> 5;             // log2(O) = 5
    const int c  = bc & (C - 1);
    const int b  = bc >> 4;            // log2(C) = 4

    // Per-chain coefficients
    const float* bw = bcf + (o * I + i) * 3;
    const float b0 = bw[0], b1 = bw[1], b2 = bw[2];
    const float* aw = acf + (o * I + i) * 2;
    const float a1 = aw[0], a2 = aw[1];

    const float* ub = u + ((size_t)b * T) * I + i;   // stride I per timestep
    float* ob = out + ((size_t)b * T) * O + o;       // stride O per timestep

    const int t0 = c * L;
    const int ts = (c == 0) ? 0 : (t0 - W);

    // FIR history (real u values, zero only before t=0)
    float u1 = (ts >= 1) ? ub[(ts - 1) * I] : 0.f;
    float u2 = (ts >= 2) ? ub[(ts - 2) * I] : 0.f;
    float y1 = 0.f, y2 = 0.f;   // zero initial state (exact for c==0)

    // Warmup region: recursion only, no output
#pragma unroll 4
    for (int t = ts; t < t0; ++t) {
        const float u0 = ub[t * I];
        const float x  = b0 * u0 + b1 * u1 + b2 * u2;
        const float y  = x - a1 * y1 - a2 * y2;
        y2 = y1; y1 = y;
        u2 = u1; u1 = u0;
    }

    // Output region: recursion + cross-lane sum over i (32 lanes)
#pragma unroll 4
    for (int t = t0; t < t0 + L; ++t) {
        const float u0 = ub[t * I];
        const float x  = b0 * u0 + b1 * u1 + b2 * u2;
        const float y  = x - a1 * y1 - a2 * y2;
        y2 = y1; y1 = y;
        u2 = u1; u1 = u0;

        // Reduce over the 32-lane i-group (xor masks <32 never cross the
        // 32-lane boundary inside the 64-lane wave)
        float s = y;
        s += __shfl_xor(s, 16);
        s += __shfl_xor(s, 8);
        s += __shfl_xor(s, 4);
        s += __shfl_xor(s, 2);
        s += __shfl_xor(s, 1);
        if (i == 0) ob[t * O] = s;
    }
}

extern "C" void kernel_launch(void* const* d_in, const int* in_sizes, int n_in,
                              void* d_out, int out_size, void* d_ws, size_t ws_size,
                              hipStream_t stream) {
    const float* u   = (const float*)d_in[0];  // (B,T,I)
    const float* bcf = (const float*)d_in[1];  // (O,I,3)
    const float* acf = (const float*)d_in[2];  // (O,I,2)
    float* out = (float*)d_out;                // (B,T,O)

    const int total_threads = B * C * O * 32;  // one thread per (chain, chunk)
    const int block = 256;
    const int grid = total_threads / block;    // 1024 blocks
    mimo_iir_kernel<<<grid, block, 0, stream>>>(u, bcf, acf, out);
}

// Round 2
// 77.959 us; speedup vs baseline: 2.4450x; 2.4450x over previous
//
#include <hip/hip_runtime.h>

// Problem dims
constexpr int B = 16, T = 4096, I = 32, O = 32;
// C chunks of L steps, W warmup steps from zero state (filters stable,
// poles <~0.75 => state error decays ~1e-8 over 64 steps; measured absmax
// 0.0156 vs threshold 0.102 last round with the same scheme).
constexpr int C = 16, L = T / C, W = 64;
constexpr int TT = 32;          // timesteps per LDS reduction tile
constexpr int NC = L / TT;      // 8 main chunks
constexpr int ROWW = 36;        // padded row stride (words): rotates bank-quads,
                                // keeps rows 16B-aligned (144B)

__global__ __launch_bounds__(256) void mimo_iir_kernel(
    const float* __restrict__ u,    // (B, T, I)
    const float* __restrict__ bcf,  // (O, I, 3)
    const float* __restrict__ acf,  // (O, I, 2)
    float* __restrict__ out)        // (B, T, O)
{
    // 8 groups/block, each 32 lanes; tile is WAVE-private (wave w owns
    // groups 2w, 2w+1) -> no __syncthreads needed anywhere.
    __shared__ float tile[8][TT][ROWW];   // 36864 B

    const int tid = threadIdx.x;
    const int i  = tid & 31;             // input channel = lane within group
    const int g  = tid >> 5;             // group within block (0..7)
    const int gg = blockIdx.x * 8 + g;   // (b, c, o), o innermost
    const int o  = gg & (O - 1);
    const int bc = gg >> 5;
    const int c  = bc & (C - 1);
    const int b  = bc >> 4;

    const float* bw = bcf + (o * I + i) * 3;
    const float b0 = bw[0], b1 = bw[1], b2 = bw[2];
    const float* aw = acf + (o * I + i) * 2;
    const float a1 = aw[0], a2 = aw[1];

    const float* ub = u + ((size_t)b * T) * I + i;
    const int t0 = c * L;

    float y1 = 0.f, y2 = 0.f, u1, u2;
    float uv[TT];                        // static-indexed -> registers

    if (c != 0) {
        // Warmup: recursion only, batched loads, no output
        const float* wp = ub + (size_t)(t0 - W) * I;
        u1 = wp[-I];
        u2 = wp[-2 * I];
#pragma unroll
        for (int blk = 0; blk < W / TT; ++blk) {
#pragma unroll
            for (int k = 0; k < TT; ++k) uv[k] = wp[k * I];
#pragma unroll
            for (int k = 0; k < TT; ++k) {
                const float u0 = uv[k];
                const float x = fmaf(b0, u0, fmaf(b1, u1, b2 * u2));
                const float y = fmaf(-a1, y1, fmaf(-a2, y2, x));
                y2 = y1; y1 = y; u2 = u1; u1 = u0;
            }
            wp += TT * I;
        }
    } else {
        u1 = 0.f; u2 = 0.f;
    }

    const float* mp = ub + (size_t)t0 * I;
    float* op = out + ((size_t)b * T + t0) * O + o;
    const float4* row = reinterpret_cast<const float4*>(&tile[g][i][0]);

    for (int ch = 0; ch < NC; ++ch) {
        // 1) batch-load 32 u values (independent, immediate offsets)
#pragma unroll
        for (int k = 0; k < TT; ++k) uv[k] = mp[k * I];
        // 2) serial recursion; ds_write_b32 off the critical path
        //    write bank = (4k+i)%32: permutation over i -> conflict-free
#pragma unroll
        for (int k = 0; k < TT; ++k) {
            const float u0 = uv[k];
            const float x = fmaf(b0, u0, fmaf(b1, u1, b2 * u2));
            const float y = fmaf(-a1, y1, fmaf(-a2, y2, x));
            y2 = y1; y1 = y; u2 = u1; u1 = u0;
            tile[g][k][i] = y;
        }
        // pin write->read order (per-wave LDS executes in order; this only
        // stops compiler motion). Tile is wave-private: no block barrier.
        __builtin_amdgcn_sched_barrier(0);
        // 3) lane tt=i reduces row i: 8x ds_read_b128, bank-quad rotates
        //    with row (stride 36 words) -> ~4 lanes/quad per instruction
        float4 s0 = row[0], s1 = row[1], s2 = row[2], s3 = row[3];
        s0 += row[4]; s1 += row[5]; s2 += row[6]; s3 += row[7];
        const float4 s = (s0 + s1) + (s2 + s3);
        op[(ch * TT + i) * (size_t)O] = (s.x + s.y) + (s.z + s.w);
        __builtin_amdgcn_sched_barrier(0);
        mp += TT * I;
    }
}

extern "C" void kernel_launch(void* const* d_in, const int* in_sizes, int n_in,
                              void* d_out, int out_size, void* d_ws, size_t ws_size,
                              hipStream_t stream) {
    const float* u   = (const float*)d_in[0];
    const float* bcf = (const float*)d_in[1];
    const float* acf = (const float*)d_in[2];
    float* out = (float*)d_out;

    const int total_threads = B * C * O * 32;   // one thread per (chain, chunk)
    const int block = 256;
    const int grid = total_threads / block;     // 1024 blocks
    mimo_iir_kernel<<<grid, block, 0, stream>>>(u, bcf, acf, out);
}